// Round 13
// baseline (46.795 us; speedup 1.0000x reference)
//
#include <hip/hip_runtime.h>

typedef unsigned int uint;
typedef unsigned short ushort_t;
typedef __attribute__((ext_vector_type(8))) short short8v;   // 8 bf16 (4 VGPRs)
typedef __attribute__((ext_vector_type(4))) float f32x4;

#define BATCH 8
#define HH 128
#define WW 128
#define CC 64
#define NPIX (BATCH * HH * WW)   // 131072
#define KK 9
#define BN_EPS 1e-3f
#define NTILE 4                   // tiles per block
#define NBLK (NPIX / 64 / NTILE)  // 512 blocks = 2 per CU, co-resident

__device__ __forceinline__ uint f2bfbits(float f) {
    uint u = __float_as_uint(f);
    return (u + 0x7fffu + ((u >> 16) & 1u)) >> 16;   // RNE
}

// ---- setup: w1 -> bf16 [d][c]; w2 -> bf16 transposed [k][d]; fold BN ----
__global__ void setup_kernel(const float* __restrict__ w1,
                             const float* __restrict__ b1,
                             const float* __restrict__ gamma,
                             const float* __restrict__ beta,
                             const float* __restrict__ bn_mean,
                             const float* __restrict__ bn_var,
                             const float* __restrict__ w2,
                             const float* __restrict__ b2,
                             ushort_t* __restrict__ w1b,    // [64][64] bf16: w1b[d][c] = w1[c][d]
                             ushort_t* __restrict__ w2bT,   // [16][64] bf16: w2bT[k][d] = w2[d][k]
                             float* __restrict__ scalef,    // [64]
                             float* __restrict__ biasf,     // [64]
                             float* __restrict__ b2f)       // [9]
{
    int t = blockIdx.x * blockDim.x + threadIdx.x;
    int nt = gridDim.x * blockDim.x;
    for (int idx = t; idx < CC * CC; idx += nt) {
        int d = idx >> 6, c = idx & 63;
        w1b[idx] = (ushort_t)f2bfbits(w1[c * CC + d]);
    }
    for (int idx = t; idx < 16 * CC; idx += nt) {
        int k = idx >> 6, d = idx & 63;
        w2bT[idx] = (k < KK) ? (ushort_t)f2bfbits(w2[d * KK + k]) : (ushort_t)0;
    }
    if (t < CC) {
        float s = gamma[t] * rsqrtf(bn_var[t] + BN_EPS);
        scalef[t] = s;
        biasf[t] = (b1[t] - bn_mean[t]) * s + beta[t];
    }
    if (t < KK) b2f[t] = b2[t];
}

// ---- persistent fused kernel: 4 tiles/block, double-buffered stage pipeline ----
__global__ __launch_bounds__(256) void invol_fused(
    const float* __restrict__ x,
    const ushort_t* __restrict__ w1b,
    const ushort_t* __restrict__ w2bT,
    const float* __restrict__ scalef,
    const float* __restrict__ biasf,
    const float* __restrict__ b2f,
    float* __restrict__ out,     // [NPIX][64]
    float* __restrict__ kout)    // [NPIX][9]
{
    __shared__ ushort_t xB[2][64][72];     // double-buffered x tile (bf16), 18.4 KB
    __shared__ ushort_t hL[4][16][72];     // per-wave h (bf16), 9.2 KB   (wave-private)
    __shared__ float    kS[64][12];        // kern per pixel, 3 KB        (wave-private rows)

    const int t = threadIdx.x;
    const int w = __builtin_amdgcn_readfirstlane(t >> 6);
    const int l = t & 63;
    const int lq = l >> 4, lr = l & 15;
    int bid = blockIdx.x;
    bid = (bid & 7) * (NBLK / 8) + (bid >> 3);   // XCD slabs (512 = 8*64, bijective)
    const int tile0 = bid * NTILE;

    // per-thread stage indices: idx = t + r*256 -> px = idx>>4, c4 = idx&15
    float4 sv[4];
    {
        const int p0s = tile0 * 64;
#pragma unroll
        for (int r = 0; r < 4; ++r) {
            int idx = t + r * 256;
            sv[r] = *(const float4*)(x + (size_t)(p0s + (idx >> 4)) * CC + (idx & 15) * 4);
        }
    }

#pragma unroll
    for (int T = 0; T < NTILE; ++T) {
        const int tile = tile0 + T;
        const int p0 = tile * 64;
        const int cur = T & 1;

        // ---- land staged regs -> LDS buf[cur] (cvt f32->bf16) ----
#pragma unroll
        for (int r = 0; r < 4; ++r) {
            int idx = t + r * 256;
            uint2 pk;
            pk.x = f2bfbits(sv[r].x) | (f2bfbits(sv[r].y) << 16);
            pk.y = f2bfbits(sv[r].z) | (f2bfbits(sv[r].w) << 16);
            *(uint2*)(&xB[cur][idx >> 4][(idx & 15) * 4]) = pk;
        }
        // ONE barrier per tile. Hazard proof: buf[cur] is re-written at tile T+2
        // (before barrier T+2); its readers ran in compute T, and every wave's
        // program order is compute(T) -> write_stage(T+1) -> barrier(T+1) ->
        // compute(T+1) -> write_stage(T+2). A wave at write_stage(T+2) has passed
        // barrier(T+1), which all waves reach only after finishing compute(T).
        __syncthreads();

        // ---- T14: issue next tile's stage loads now; in flight under compute ----
        {
            const int nxt = (T < NTILE - 1) ? tile + 1 : tile;   // clamp (harmless reload)
            const int p0s = nxt * 64;
#pragma unroll
            for (int r = 0; r < 4; ++r) {
                int idx = t + r * 256;
                sv[r] = *(const float4*)(x + (size_t)(p0s + (idx >> 4)) * CC + (idx & 15) * 4);
            }
        }

        // ---- GEMM1: wave w owns px [w*16,w*16+16); A from LDS (r6/r12 recipe) ----
        {
            short8v af[2];
#pragma unroll
            for (int ks = 0; ks < 2; ++ks)
                af[ks] = *(const short8v*)(&xB[cur][w * 16 + lr][ks * 32 + lq * 8]);

            f32x4 acc[4];
#pragma unroll
            for (int n = 0; n < 4; ++n) acc[n] = (f32x4){0.f, 0.f, 0.f, 0.f};
#pragma unroll
            for (int ks = 0; ks < 2; ++ks)
#pragma unroll
                for (int n = 0; n < 4; ++n) {
                    short8v bf = *(const short8v*)(w1b + (n * 16 + lr) * CC + ks * 32 + lq * 8);
                    acc[n] = __builtin_amdgcn_mfma_f32_16x16x32_bf16(af[ks], bf, acc[n], 0, 0, 0);
                }
            // epilogue: BN+ReLU -> bf16 -> hL (C layout: row=px=lq*4+r, col=d=n*16+lr)
#pragma unroll
            for (int n = 0; n < 4; ++n) {
                const int d = n * 16 + lr;
                const float s = scalef[d], bb = biasf[d];
#pragma unroll
                for (int r = 0; r < 4; ++r) {
                    float hv = fmaxf(fmaf(acc[n][r], s, bb), 0.f);
                    hL[w][lq * 4 + r][d] = (ushort_t)f2bfbits(hv);
                }
            }
        }
        // same-wave LDS handoff (compiler lgkmcnt; r9/r12-proven)

        // ---- GEMM2: kern = h @ w2 + b2 via MFMA (M=16, N=16 pad, K=64; r9 recipe) ----
        {
            f32x4 acc2 = (f32x4){0.f, 0.f, 0.f, 0.f};
#pragma unroll
            for (int ks = 0; ks < 2; ++ks) {
                short8v a2  = *(const short8v*)(&hL[w][lr][ks * 32 + lq * 8]);
                short8v b2v = *(const short8v*)(w2bT + lr * CC + ks * 32 + lq * 8);
                acc2 = __builtin_amdgcn_mfma_f32_16x16x32_bf16(a2, b2v, acc2, 0, 0, 0);
            }
            if (lr < KK) {
                const float bk = b2f[lr];
#pragma unroll
                for (int r = 0; r < 4; ++r)
                    kS[w * 16 + lq * 4 + r][lr] = acc2[r] + bk;
            }
        }
        // same-wave handoff; dense kout drain: 36 float4 per wave (rows w*16..+16)
        {
            float* kbase = kout + (size_t)(p0 + w * 16) * KK;
            if (l < 36) {
                float v[4];
#pragma unroll
                for (int e = 0; e < 4; ++e) {
                    int f = l * 4 + e;
                    v[e] = kS[w * 16 + f / KK][f % KK];
                }
                *(f32x4*)(kbase + l * 4) = (f32x4){v[0], v[1], v[2], v[3]};
            }
        }

        // ---- involution: thread = (pxl = t>>2 in wave's px range, 16-ch quarter) ----
        {
            const int pxl = t >> 2;
            const int c0i = (t & 3) * 16;
            const int p = p0 + pxl;
            const int b = p >> 14;
            const int i = (p >> 7) & 127;     // uniform per tile (64 px in half a row)
            const int j = p & 127;

            float kern[KK];
#pragma unroll
            for (int k = 0; k < KK; ++k) kern[k] = kS[pxl][k];

            float4 accv[4];
#pragma unroll
            for (int f = 0; f < 4; ++f) accv[f] = make_float4(0.f, 0.f, 0.f, 0.f);

#pragma unroll
            for (int ti = -1; ti <= 1; ++ti) {
                int ii = i + ti;
                if (ii < 0 || ii >= HH) continue;          // wave-uniform (zero-pad)
                const float* rowp = x + ((size_t)b * HH + ii) * WW * CC;
#pragma unroll
                for (int tj = -1; tj <= 1; ++tj) {
                    const int tap = (ti + 1) * 3 + (tj + 1);
                    int jj = j + tj;
                    bool valid = (jj >= 0) && (jj < WW);
                    float kv = valid ? kern[tap] : 0.f;
                    int jjc = min(max(jj, 0), WW - 1);
                    const float4* np = (const float4*)(rowp + (size_t)jjc * CC + c0i);
#pragma unroll
                    for (int f = 0; f < 4; ++f) {
                        float4 v = np[f];
                        accv[f].x = fmaf(kv, v.x, accv[f].x);
                        accv[f].y = fmaf(kv, v.y, accv[f].y);
                        accv[f].z = fmaf(kv, v.z, accv[f].z);
                        accv[f].w = fmaf(kv, v.w, accv[f].w);
                    }
                }
            }

            float4* op = (float4*)(out + (size_t)p * CC + c0i);
#pragma unroll
            for (int f = 0; f < 4; ++f) op[f] = accv[f];
        }
    }
}

extern "C" void kernel_launch(void* const* d_in, const int* in_sizes, int n_in,
                              void* d_out, int out_size, void* d_ws, size_t ws_size,
                              hipStream_t stream) {
    const float* x       = (const float*)d_in[0];
    const float* w1      = (const float*)d_in[1];
    const float* b1      = (const float*)d_in[2];
    const float* gamma   = (const float*)d_in[3];
    const float* beta    = (const float*)d_in[4];
    const float* bn_mean = (const float*)d_in[5];
    const float* bn_var  = (const float*)d_in[6];
    const float* w2      = (const float*)d_in[7];
    const float* b2      = (const float*)d_in[8];

    ushort_t* w1b  = (ushort_t*)d_ws;                // 4096 ush = 8192 B
    ushort_t* w2bT = w1b + CC * CC;                  // 1024 ush = 2048 B
    float* scalef  = (float*)(w2bT + 16 * CC);       // 64
    float* biasf   = scalef + CC;                    // 64
    float* b2f     = biasf + CC;                     // 9

    float* out  = (float*)d_out;
    float* kout = out + (size_t)NPIX * CC;

    hipLaunchKernelGGL(setup_kernel, dim3(20), dim3(256), 0, stream,
                       w1, b1, gamma, beta, bn_mean, bn_var, w2, b2,
                       w1b, w2bT, scalef, biasf, b2f);

    hipLaunchKernelGGL(invol_fused, dim3(NBLK), dim3(256), 0, stream,
                       x, w1b, w2bT, scalef, biasf, b2f, out, kout);
}

// Round 14
// 46.276 us; speedup vs baseline: 1.0112x; 1.0112x over previous
//
#include <hip/hip_runtime.h>

typedef unsigned int uint;
typedef unsigned short ushort_t;
typedef __attribute__((ext_vector_type(8))) short short8v;   // 8 bf16 (4 VGPRs)
typedef __attribute__((ext_vector_type(4))) float f32x4;

#define BATCH 8
#define HH 128
#define WW 128
#define CC 64
#define NPIX (BATCH * HH * WW)   // 131072
#define KK 9
#define BN_EPS 1e-3f

__device__ __forceinline__ uint f2bfbits(float f) {
    uint u = __float_as_uint(f);
    return (u + 0x7fffu + ((u >> 16) & 1u)) >> 16;   // RNE
}

// ---- setup: w1 -> bf16 [d][c]; w2 -> bf16 transposed [k][d]; fold BN ----
__global__ void setup_kernel(const float* __restrict__ w1,
                             const float* __restrict__ b1,
                             const float* __restrict__ gamma,
                             const float* __restrict__ beta,
                             const float* __restrict__ bn_mean,
                             const float* __restrict__ bn_var,
                             const float* __restrict__ w2,
                             const float* __restrict__ b2,
                             ushort_t* __restrict__ w1b,    // [64][64] bf16: w1b[d][c] = w1[c][d]
                             ushort_t* __restrict__ w2bT,   // [16][64] bf16: w2bT[k][d] = w2[d][k]
                             float* __restrict__ scalef,    // [64]
                             float* __restrict__ biasf,     // [64]
                             float* __restrict__ b2f)       // [9]
{
    int t = blockIdx.x * blockDim.x + threadIdx.x;
    int nt = gridDim.x * blockDim.x;
    for (int idx = t; idx < CC * CC; idx += nt) {
        int d = idx >> 6, c = idx & 63;
        w1b[idx] = (ushort_t)f2bfbits(w1[c * CC + d]);
    }
    for (int idx = t; idx < 16 * CC; idx += nt) {
        int k = idx >> 6, d = idx & 63;
        w2bT[idx] = (k < KK) ? (ushort_t)f2bfbits(w2[d * KK + k]) : (ushort_t)0;
    }
    if (t < CC) {
        float s = gamma[t] * rsqrtf(bn_var[t] + BN_EPS);
        scalef[t] = s;
        biasf[t] = (b1[t] - bn_mean[t]) * s + beta[t];
    }
    if (t < KK) b2f[t] = b2[t];
}

// ---- fused, barrier-free, continuous load stream. wave = 16 px end-to-end ----
__global__ __launch_bounds__(256) void invol_fused(
    const float* __restrict__ x,
    const ushort_t* __restrict__ w1b,
    const ushort_t* __restrict__ w2bT,
    const float* __restrict__ scalef,
    const float* __restrict__ biasf,
    const float* __restrict__ b2f,
    float* __restrict__ out,     // [NPIX][64]
    float* __restrict__ kout)    // [NPIX][9]
{
    __shared__ ushort_t hL[4][16][72];     // per-wave h (bf16), 9.2 KB (wave-private)
    __shared__ float    kS[64][12];        // kern per pixel, 3 KB (wave-private rows)

    const int t = threadIdx.x;
    const int w = __builtin_amdgcn_readfirstlane(t >> 6);
    const int l = t & 63;
    const int lq = l >> 4, lr = l & 15;
    int bid = blockIdx.x;
    bid = (bid & 7) * 256 + (bid >> 3);    // XCD swizzle (2048 = 8*256, bijective)
    const int p0 = bid * 64;

    // involution thread identity (t>>2 lies in wave w's own px range)
    const int pxl = t >> 2;
    const int c0i = (t & 3) * 16;
    const int p = p0 + pxl;
    const int b = p >> 14;
    const int i = (p >> 7) & 127;          // uniform per block (64 px in half a row)
    const int j = p & 127;

    // ---- issue A-frag loads FIRST (oldest -> GEMM1's wait leaves taps in flight) ----
    const float* xr = x + (size_t)(p0 + w * 16 + lr) * CC;
    float4 a00 = *(const float4*)(xr + lq * 8);
    float4 a01 = *(const float4*)(xr + lq * 8 + 4);
    float4 a10 = *(const float4*)(xr + 32 + lq * 8);
    float4 a11 = *(const float4*)(xr + 32 + lq * 8 + 4);

    // ---- issue row -1 tap loads (clamped addresses; weights zeroed later) ----
    float4 gm[3][4];
    {
        const int im1 = max(i - 1, 0);
        const float* rowm = x + ((size_t)b * HH + im1) * WW * CC;
#pragma unroll
        for (int tj = 0; tj < 3; ++tj) {
            int jc = min(max(j + tj - 1, 0), WW - 1);
            const float4* np = (const float4*)(rowm + (size_t)jc * CC + c0i);
#pragma unroll
            for (int f = 0; f < 4; ++f) gm[tj][f] = np[f];
        }
    }

    // ---- cvt A -> bf16 frags; GEMM1 (r6/r12-proven recipe) ----
    {
        short8v af[2];
        union { uint4 u; short8v s; } cv;
        cv.u.x = f2bfbits(a00.x) | (f2bfbits(a00.y) << 16);
        cv.u.y = f2bfbits(a00.z) | (f2bfbits(a00.w) << 16);
        cv.u.z = f2bfbits(a01.x) | (f2bfbits(a01.y) << 16);
        cv.u.w = f2bfbits(a01.z) | (f2bfbits(a01.w) << 16);
        af[0] = cv.s;
        cv.u.x = f2bfbits(a10.x) | (f2bfbits(a10.y) << 16);
        cv.u.y = f2bfbits(a10.z) | (f2bfbits(a10.w) << 16);
        cv.u.z = f2bfbits(a11.x) | (f2bfbits(a11.y) << 16);
        cv.u.w = f2bfbits(a11.z) | (f2bfbits(a11.w) << 16);
        af[1] = cv.s;

        f32x4 acc[4];
#pragma unroll
        for (int n = 0; n < 4; ++n) acc[n] = (f32x4){0.f, 0.f, 0.f, 0.f};
#pragma unroll
        for (int ks = 0; ks < 2; ++ks)
#pragma unroll
            for (int n = 0; n < 4; ++n) {
                short8v bf = *(const short8v*)(w1b + (n * 16 + lr) * CC + ks * 32 + lq * 8);
                acc[n] = __builtin_amdgcn_mfma_f32_16x16x32_bf16(af[ks], bf, acc[n], 0, 0, 0);
            }
        // epilogue: BN+ReLU -> bf16 -> hL (C layout: row=px=lq*4+r, col=d=n*16+lr)
#pragma unroll
        for (int n = 0; n < 4; ++n) {
            const int d = n * 16 + lr;
            const float s = scalef[d], bb = biasf[d];
#pragma unroll
            for (int r = 0; r < 4; ++r) {
                float hv = fmaxf(fmaf(acc[n][r], s, bb), 0.f);
                hL[w][lq * 4 + r][d] = (ushort_t)f2bfbits(hv);
            }
        }
    }
    // same-wave LDS handoff (compiler lgkmcnt; r9/r12-proven)

    // ---- GEMM2: kern = h @ w2 + b2 via MFMA (M=16, N=16 pad, K=64; r9 recipe) ----
    {
        f32x4 acc2 = (f32x4){0.f, 0.f, 0.f, 0.f};
#pragma unroll
        for (int ks = 0; ks < 2; ++ks) {
            short8v a2  = *(const short8v*)(&hL[w][lr][ks * 32 + lq * 8]);
            short8v b2v = *(const short8v*)(w2bT + lr * CC + ks * 32 + lq * 8);
            acc2 = __builtin_amdgcn_mfma_f32_16x16x32_bf16(a2, b2v, acc2, 0, 0, 0);
        }
        if (lr < KK) {
            const float bk = b2f[lr];
#pragma unroll
            for (int r = 0; r < 4; ++r)
                kS[w * 16 + lq * 4 + r][lr] = acc2[r] + bk;
        }
    }
    // same-wave handoff; dense kout drain: 36 float4 per wave
    {
        float* kbase = kout + (size_t)(p0 + w * 16) * KK;
        if (l < 36) {
            float v[4];
#pragma unroll
            for (int e = 0; e < 4; ++e) {
                int f = l * 4 + e;
                v[e] = kS[w * 16 + f / KK][f % KK];
            }
            *(f32x4*)(kbase + l * 4) = (f32x4){v[0], v[1], v[2], v[3]};
        }
    }

    // ---- involution, software-pipelined rows ----
    float kern[KK];
#pragma unroll
    for (int k = 0; k < KK; ++k) kern[k] = kS[pxl][k];

    float4 accv[4];
#pragma unroll
    for (int f = 0; f < 4; ++f) accv[f] = make_float4(0.f, 0.f, 0.f, 0.f);

    // issue row 0 taps (younger than row -1; consuming row -1 won't drain them)
    float4 g0[3][4];
    {
        const float* row0 = x + ((size_t)b * HH + i) * WW * CC;
#pragma unroll
        for (int tj = 0; tj < 3; ++tj) {
            int jc = min(max(j + tj - 1, 0), WW - 1);
            const float4* np = (const float4*)(row0 + (size_t)jc * CC + c0i);
#pragma unroll
            for (int f = 0; f < 4; ++f) g0[tj][f] = np[f];
        }
    }

    // consume row -1
#pragma unroll
    for (int tj = 0; tj < 3; ++tj) {
        int jj = j + tj - 1;
        bool valid = (i > 0) && (jj >= 0) && (jj < WW);
        float kv = valid ? kern[tj] : 0.f;
#pragma unroll
        for (int f = 0; f < 4; ++f) {
            accv[f].x = fmaf(kv, gm[tj][f].x, accv[f].x);
            accv[f].y = fmaf(kv, gm[tj][f].y, accv[f].y);
            accv[f].z = fmaf(kv, gm[tj][f].z, accv[f].z);
            accv[f].w = fmaf(kv, gm[tj][f].w, accv[f].w);
        }
    }

    // issue row +1 taps
    float4 g1[3][4];
    {
        const int ip1 = min(i + 1, HH - 1);
        const float* rowp = x + ((size_t)b * HH + ip1) * WW * CC;
#pragma unroll
        for (int tj = 0; tj < 3; ++tj) {
            int jc = min(max(j + tj - 1, 0), WW - 1);
            const float4* np = (const float4*)(rowp + (size_t)jc * CC + c0i);
#pragma unroll
            for (int f = 0; f < 4; ++f) g1[tj][f] = np[f];
        }
    }

    // consume row 0
#pragma unroll
    for (int tj = 0; tj < 3; ++tj) {
        int jj = j + tj - 1;
        bool valid = (jj >= 0) && (jj < WW);
        float kv = valid ? kern[3 + tj] : 0.f;
#pragma unroll
        for (int f = 0; f < 4; ++f) {
            accv[f].x = fmaf(kv, g0[tj][f].x, accv[f].x);
            accv[f].y = fmaf(kv, g0[tj][f].y, accv[f].y);
            accv[f].z = fmaf(kv, g0[tj][f].z, accv[f].z);
            accv[f].w = fmaf(kv, g0[tj][f].w, accv[f].w);
        }
    }

    // consume row +1
#pragma unroll
    for (int tj = 0; tj < 3; ++tj) {
        int jj = j + tj - 1;
        bool valid = (i < HH - 1) && (jj >= 0) && (jj < WW);
        float kv = valid ? kern[6 + tj] : 0.f;
#pragma unroll
        for (int f = 0; f < 4; ++f) {
            accv[f].x = fmaf(kv, g1[tj][f].x, accv[f].x);
            accv[f].y = fmaf(kv, g1[tj][f].y, accv[f].y);
            accv[f].z = fmaf(kv, g1[tj][f].z, accv[f].z);
            accv[f].w = fmaf(kv, g1[tj][f].w, accv[f].w);
        }
    }

    float4* op = (float4*)(out + (size_t)p * CC + c0i);
#pragma unroll
    for (int f = 0; f < 4; ++f) op[f] = accv[f];
}

extern "C" void kernel_launch(void* const* d_in, const int* in_sizes, int n_in,
                              void* d_out, int out_size, void* d_ws, size_t ws_size,
                              hipStream_t stream) {
    const float* x       = (const float*)d_in[0];
    const float* w1      = (const float*)d_in[1];
    const float* b1      = (const float*)d_in[2];
    const float* gamma   = (const float*)d_in[3];
    const float* beta    = (const float*)d_in[4];
    const float* bn_mean = (const float*)d_in[5];
    const float* bn_var  = (const float*)d_in[6];
    const float* w2      = (const float*)d_in[7];
    const float* b2      = (const float*)d_in[8];

    ushort_t* w1b  = (ushort_t*)d_ws;                // 4096 ush = 8192 B
    ushort_t* w2bT = w1b + CC * CC;                  // 1024 ush = 2048 B
    float* scalef  = (float*)(w2bT + 16 * CC);       // 64
    float* biasf   = scalef + CC;                    // 64
    float* b2f     = biasf + CC;                     // 9

    float* out  = (float*)d_out;
    float* kout = out + (size_t)NPIX * CC;

    hipLaunchKernelGGL(setup_kernel, dim3(20), dim3(256), 0, stream,
                       w1, b1, gamma, beta, bn_mean, bn_var, w2, b2,
                       w1b, w2bT, scalef, biasf, b2f);

    hipLaunchKernelGGL(invol_fused, dim3(NPIX / 64), dim3(256), 0, stream,
                       x, w1b, w2bT, scalef, biasf, b2f, out, kout);
}